// Round 5
// baseline (56638.019 us; speedup 1.0000x reference)
//
#include <hip/hip_runtime.h>
#include <hip/hip_bf16.h>
#include <hip/hip_cooperative_groups.h>

namespace cg = cooperative_groups;

// ---------------------------------------------------------------------------
// StandardMRALSTM — round 5: single persistent cooperative scan kernel.
//  * 258 wavefront phases (tau=2t+k) inside ONE kernel, grid.sync() between
//    GEMM stage and gates stage (2 syncs/phase) — removes ~516 x 5us dispatch
//    serialization measured across rounds 3/4.
//  * gates: block-level LDS reduction -> 1 atomicAdd per block (was 8).
//  * hist layout [tk][j][b]: gates writes coalesced (lane=b).
//  * GEMM math / partials / s-protocol identical to round 4 (passing).
//  * Fallback: per-phase dispatch pair if cooperative launch unavailable.
// ---------------------------------------------------------------------------

#define LL 4
#define HH 512
#define TS 128
#define GG 16
#define BB 64
#define FF 64
#define TT 4
#define FIVE_H 2560
#define LBH (LL * BB * HH)

typedef unsigned short u16;
typedef unsigned int u32;
typedef unsigned long long u64;

#define SG_OFF    64
#define ZALL_OFF  1024
#define ZMASK_OFF 2048
#define C_OFF     4096
#define PING_OFF  (C_OFF + LBH)                       // 135168
#define PART_OFF  (PING_OFF + 2 * LBH)                // 397312
#define PART_SEG  (12 * 4 * HH * BB)                  // 1572864 floats per seg
#define HIST_OFF  (PART_OFF + 2 * PART_SEG)           // 3543040 (u16 region)

__device__ __forceinline__ float bf2f(u16 u) { return __uint_as_float(((u32)u) << 16); }
__device__ __forceinline__ float2 bf2x2(u32 u) {
    float2 r;
    r.x = __uint_as_float(u << 16);
    r.y = __uint_as_float(u & 0xFFFF0000u);
    return r;
}
__device__ __forceinline__ u16 f2bf_rne(float f) {
    u32 x = __float_as_uint(f);
    return (u16)((x + 0x7FFFu + ((x >> 16) & 1u)) >> 16);
}
__device__ __forceinline__ float sigm(float x) { return 1.f / (1.f + expf(-x)); }

template <bool BF>
__device__ __forceinline__ float ldv(const void* p, size_t i) {
    return BF ? bf2f(((const u16*)p)[i]) : ((const float*)p)[i];
}

template <bool BF>
__device__ __forceinline__ float dot16(const void* row, const float* xs) {
    float s = 0.f;
    if (BF) {
        const uint4* p = (const uint4*)row;
        uint4 a = p[0], b4 = p[1];
        float2 v;
        v = bf2x2(a.x);  s += v.x * xs[0]  + v.y * xs[1];
        v = bf2x2(a.y);  s += v.x * xs[2]  + v.y * xs[3];
        v = bf2x2(a.z);  s += v.x * xs[4]  + v.y * xs[5];
        v = bf2x2(a.w);  s += v.x * xs[6]  + v.y * xs[7];
        v = bf2x2(b4.x); s += v.x * xs[8]  + v.y * xs[9];
        v = bf2x2(b4.y); s += v.x * xs[10] + v.y * xs[11];
        v = bf2x2(b4.z); s += v.x * xs[12] + v.y * xs[13];
        v = bf2x2(b4.w); s += v.x * xs[14] + v.y * xs[15];
    } else {
        const float4* p = (const float4*)row;
#pragma unroll
        for (int i = 0; i < 4; ++i) {
            float4 v = p[i];
            s += v.x * xs[4 * i] + v.y * xs[4 * i + 1] + v.z * xs[4 * i + 2] + v.w * xs[4 * i + 3];
        }
    }
    return s;
}

// ---- init A: zero c + sgsum, sniff dtype ----------------------------------
__global__ void initA_kernel(const u16* __restrict__ bnd_raw, float* __restrict__ ws) {
    size_t i = (size_t)blockIdx.x * 256 + threadIdx.x;
    if (i < LBH) ws[C_OFF + i] = 0.f;
    if (i < 512) ws[SG_OFF + i] = 0.f;
    if (i == 0) {
        int bf = 1;
        for (int j = 0; j < 32; ++j) {
            float v = bf2f(bnd_raw[2 * j]);
            if (!(v >= 0.f && v <= 1.f)) bf = 0;
        }
        ((int*)ws)[0] = bf;
    }
}

// ---- init B: per-(t,k) z bitmask over batches ------------------------------
template <bool BF>
__device__ void initB_body(const void* xin, float* ws) {
    int tk = blockIdx.x;
    int t = tk >> 2, k = tk & 3;
    int b = threadIdx.x;
    bool z = false;
    size_t base = (size_t)b * TS * FF + (size_t)t * FF + k * GG;
#pragma unroll
    for (int g = 0; g < GG; ++g) {
        float v = ldv<BF>(xin, base + g);
        z |= !(v != v);
    }
    u64 m = __ballot(z);
    if (b == 0) {
        ((u64*)(ws + ZMASK_OFF))[tk] = m;
        ((int*)(ws + ZALL_OFF))[tk] = (m == ~0ull) ? 1 : 0;
    }
}
__global__ __launch_bounds__(64) void initB_kernel(const void* xin, float* ws) {
    int mode = ((const int*)ws)[0];
    if (mode) initB_body<true>(xin, ws);
    else      initB_body<false>(xin, ws);
}

// ---- per-phase metadata (grid-uniform) -------------------------------------
template <bool BF>
__device__ __forceinline__ void phase_meta(const void* bnd, const float* ws,
                                           int tau, int s,
                                           int& t, int& k, int& mcase, int& azf, int& nblk) {
    k = (tau & 1) + 2 * s;
    t = (tau - k) >> 1;
    mcase = 4; azf = 0; nblk = 0;
    if (t < 0 || t >= TS) { t = -1; return; }
    const float* sgsum = ws + SG_OFF;
    bool p_hi = (t == 0) ? (ldv<BF>(bnd, (size_t)k * TS) > 0.5f) : (sgsum[(t - 1) * 4 + k] > 16384.f);
    bool l_hi = (k == 0) ? (ldv<BF>(bnd, (size_t)t) > 0.5f) : (sgsum[t * 4 + (k - 1)] > 16384.f);
    mcase = p_hi ? (l_hi ? 3 : 2) : (l_hi ? 1 : 4);
    azf = ((const int*)(ws + ZALL_OFF))[t * 4 + k] ? 0 : 1;
    if (mcase == 4) return;
    int gs = (mcase == 1) ? 0 : 1, ng = 4 - gs;
    int nW = (t > 0) ? ng : 0;
    int nU = ((mcase == 1 || mcase == 3) && k > 0) ? ng : 0;
    int nV = azf ? nU : 0;
    nblk = (nW + nU + nV) * 32;
}

// ---- one GEMM tile slot (identical math to round 4) ------------------------
template <bool BF>
__device__ void gemm_slot(const void* Wm, const void* Zm, const void* Um, const void* Vm,
                          float* ws, float* wt, float* ht,
                          int seg, int idx, int t, int k, int mcase, int azf) {
    int tid = threadIdx.x;
    int q = idx & 3, sub = (idx >> 2) & 7, unit = idx >> 5;
    int gs = (mcase == 1) ? 0 : 1, ng = 4 - gs;
    int nW = (t > 0) ? ng : 0;
    int nU = ((mcase == 1 || mcase == 3) && k > 0) ? ng : 0;

    int mat, g;
    if (unit < nW)            { mat = (mcase == 1) ? 0 : 1; g = gs + unit; }
    else if (unit < nW + nU)  { mat = 2; g = gs + unit - nW; }
    else                      { mat = 3; g = gs + unit - nW - nU; }

    const void* M = (mat == 0) ? Wm : (mat == 1) ? Zm : (mat == 2) ? Um : Vm;
    int RS = (mat == 2) ? (HH + GG) : HH;
    int gbase = (g < 3) ? g * 512 : 2048;
    size_t mbase = (size_t)k * FIVE_H * RS + (size_t)(gbase + sub * 64) * RS + q * 128;
    int kn = (k + 1 < LL) ? k + 1 : LL - 1;
    const float* ping = ws + PING_OFF;
    const float* prev = ping + (size_t)((t + 1) & 1) * LBH;   // [k][c][b]
    const float* cur  = ping + (size_t)(t & 1) * LBH;
    const float* hv = (mat == 0) ? prev + (size_t)k * HH * BB
                    : (mat == 1) ? prev + (size_t)kn * HH * BB
                                 : cur + (size_t)(k - 1) * HH * BB;
    int path = (mat <= 1) ? 0 : (mat == 2 ? 1 : 2);

    int rg = tid >> 4, bg = tid & 15;
    float acc[4][4] = {{0.f}};

    for (int half = 0; half < 2; ++half) {
        int sr = tid >> 2, scg = (tid & 3) * 16;
        size_t rowoff = mbase + (size_t)sr * RS + half * 64 + scg;
#pragma unroll
        for (int i = 0; i < 4; ++i) {
            float4 v;
            if (BF) {
                uint2 u2 = *(const uint2*)((const u16*)M + rowoff + 4 * i);
                float2 a = bf2x2(u2.x), c2 = bf2x2(u2.y);
                v = make_float4(a.x, a.y, c2.x, c2.y);
            } else {
                v = *(const float4*)((const float*)M + rowoff + 4 * i);
            }
            *(float4*)&wt[sr * 68 + scg + 4 * i] = v;
        }
        int hc = tid >> 2, hb = (tid & 3) * 16;
        const float* hrow = hv + (size_t)(q * 128 + half * 64 + hc) * BB + hb;
#pragma unroll
        for (int i = 0; i < 4; ++i)
            *(float4*)&ht[hc * 68 + hb + 4 * i] = *(const float4*)(hrow + 4 * i);
        __syncthreads();
#pragma unroll 4
        for (int kk4 = 0; kk4 < 64; kk4 += 4) {
            float w[4][4], h[4][4];
#pragma unroll
            for (int j = 0; j < 4; ++j)
                *(float4*)w[j] = *(const float4*)&wt[(rg * 4 + j) * 68 + kk4];
#pragma unroll
            for (int j = 0; j < 4; ++j)
                *(float4*)h[j] = *(const float4*)&ht[(kk4 + j) * 68 + bg * 4];
#pragma unroll
            for (int rj = 0; rj < 4; ++rj)
#pragma unroll
                for (int bj = 0; bj < 4; ++bj)
#pragma unroll
                    for (int j = 0; j < 4; ++j)
                        acc[rj][bj] += w[rj][j] * h[j][bj];
        }
        __syncthreads();
    }

    float* pout = ws + PART_OFF + (size_t)seg * PART_SEG +
                  ((size_t)(path * 4 + q) * 4 + g) * (size_t)HH * BB;
#pragma unroll
    for (int rj = 0; rj < 4; ++rj) {
        float4 vv = make_float4(acc[rj][0], acc[rj][1], acc[rj][2], acc[rj][3]);
        *(float4*)&pout[(size_t)(sub * 64 + rg * 4 + rj) * BB + bg * 4] = vv;
    }
}

// ---- one gates slot (round 4 + LDS sg-reduction + coalesced hist) ----------
template <bool BF>
__device__ void gates_slot(const void* xin, const void* Um, const void* Jm,
                           const void* bbias, float* ws, float* smem,
                           int seg, int jblk, int t, int k, int mcase, int azf) {
    float (*xs)[GG + 1] = (float (*)[GG + 1])smem;       // 64 x 17
    float* red = smem + BB * (GG + 1);                   // 4
    int tid = threadIdx.x;
    int j = jblk * 4 + (tid >> 6);
    int b = tid & 63;

    {
        int b2 = tid >> 2, i0 = (tid & 3) * 4;
#pragma unroll
        for (int i = 0; i < 4; ++i) {
            float v = ldv<BF>(xin, (size_t)b2 * TS * FF + (size_t)t * FF + k * GG + i0 + i);
            xs[b2][i0 + i] = (v != v) ? 0.f : v;
        }
    }
    __syncthreads();
    u64 zm = ((const u64*)(ws + ZMASK_OFF))[t * 4 + k];
    bool zb = (zm >> b) & 1ull;

    float* cbuf = ws + C_OFF;                            // [k][j][b]
    const float* part = ws + PART_OFF + (size_t)seg * PART_SEG;
    float* cur = ws + PING_OFF + (size_t)(t & 1) * LBH;
    const float* prev = ws + PING_OFF + (size_t)((t + 1) & 1) * LBH;
    u16* hist = (u16*)(ws + HIST_OFF);
    size_t sidx = ((size_t)k * HH + j) * BB + b;

    float hn, sgv;
    if (mcase == 4) {
        float c = cbuf[sidx];
        float o = sigm(ldv<BF>(bbias, (size_t)k * FIVE_H + 1536 + j));
        hn = o * tanhf(c);
        float bsg = ldv<BF>(bbias, (size_t)k * FIVE_H + 2048 + j);
        sgv = fminf(fmaxf((bsg + 1.f) * 0.5f, 0.f), 1.f);
    } else {
        bool hasWZ = (t > 0);
        bool hasU = (k > 0) && (mcase != 2);
        const float* xv = &xs[b][0];

        auto psum = [&](int path, int g) -> float {
            float s = 0.f;
#pragma unroll
            for (int qq = 0; qq < 4; ++qq)
                s += part[(((size_t)(path * 4 + qq) * 4 + g) * HH + j) * BB + b];
            return s;
        };
        auto pre = [&](int g) -> float {
            int gb = (g < 3) ? g * 512 : 2048;
            float s = ldv<BF>(bbias, (size_t)k * FIVE_H + gb + j);
            if (hasWZ) s += psum(0, g);
            if (mcase == 2) {
                if (zb) {
                    const void* row = BF ? (const void*)((const u16*)Jm + (size_t)k * FIVE_H * GG + (size_t)(gb + j) * GG)
                                         : (const void*)((const float*)Jm + (size_t)k * FIVE_H * GG + (size_t)(gb + j) * GG);
                    s += dot16<BF>(row, xv);
                }
            } else {
                if (zb) {
                    if (hasU) s += psum(1, g);
                    const void* row = BF ? (const void*)((const u16*)Um + (size_t)k * FIVE_H * (HH + GG) + (size_t)(gb + j) * (HH + GG) + HH)
                                         : (const void*)((const float*)Um + (size_t)k * FIVE_H * (HH + GG) + (size_t)(gb + j) * (HH + GG) + HH);
                    s += dot16<BF>(row, xv);
                } else {
                    if (hasU && azf) s += psum(2, g);
                }
            }
            return s;
        };
        float preg = pre(1), prei = pre(2), presg = pre(3);
        float gg = tanhf(preg), ii = sigm(prei);
        float cnew;
        if (mcase == 1) {
            float f = sigm(pre(0));
            cnew = f * cbuf[sidx] + ii * gg;
        } else {
            cnew = ii * gg;
        }
        cbuf[sidx] = cnew;
        hn = (t > 0) ? prev[sidx] : 0.f;
        sgv = fminf(fmaxf((presg + 1.f) * 0.5f, 0.f), 1.f);
    }
    cur[sidx] = hn;
    hist[((size_t)(t * 4 + k) * HH + j) * BB + b] = f2bf_rne(hn);  // coalesced (lane=b)

    float s = sgv;
#pragma unroll
    for (int off = 32; off > 0; off >>= 1) s += __shfl_down(s, off);
    if ((tid & 63) == 0) red[tid >> 6] = s;
    __syncthreads();
    if (tid == 0)
        atomicAdd(&ws[SG_OFF + t * 4 + k], red[0] + red[1] + red[2] + red[3]);
}

// ---- persistent cooperative scan -------------------------------------------
template <bool BF>
__device__ void scan_body(const void* xin, const void* Wm, const void* Zm,
                          const void* Um, const void* Vm, const void* Jm,
                          const void* bbias, const void* bnd,
                          float* ws, float* smem) {
    cg::grid_group grid = cg::this_grid();
    for (int tau = 0; tau < 2 * TS + LL - 2; ++tau) {            // 258 phases
        int t0, k0, m0, a0, n0, t1, k1, m1, a1, n1;
        phase_meta<BF>(bnd, ws, tau, 0, t0, k0, m0, a0, n0);
        phase_meta<BF>(bnd, ws, tau, 1, t1, k1, m1, a1, n1);
        int total = n0 + n1;
        for (int bid = blockIdx.x; bid < total; bid += gridDim.x) {
            if (bid < n0) gemm_slot<BF>(Wm, Zm, Um, Vm, ws, smem, smem + 4352, 0, bid, t0, k0, m0, a0);
            else          gemm_slot<BF>(Wm, Zm, Um, Vm, ws, smem, smem + 4352, 1, bid - n0, t1, k1, m1, a1);
        }
        __threadfence();
        grid.sync();
        if (blockIdx.x < 256) {
            int seg = blockIdx.x >> 7, jblk = blockIdx.x & 127;
            int t = seg ? t1 : t0, k = seg ? k1 : k0;
            int mc = seg ? m1 : m0, az = seg ? a1 : a0;
            if (t >= 0)
                gates_slot<BF>(xin, Um, Jm, bbias, ws, smem, seg, jblk, t, k, mc, az);
        }
        __threadfence();
        grid.sync();
    }
}

__global__ __launch_bounds__(256) void scan_kernel(
    const void* xin, const void* Wm, const void* Zm, const void* Um,
    const void* Vm, const void* Jm, const void* bbias, const void* bnd,
    float* ws) {
    __shared__ float smem[2 * 64 * 68];
    int mode = ((const int*)ws)[0];   // grid-uniform
    if (mode) scan_body<true>(xin, Wm, Zm, Um, Vm, Jm, bbias, bnd, ws, smem);
    else      scan_body<false>(xin, Wm, Zm, Um, Vm, Jm, bbias, bnd, ws, smem);
}

// ---- fallback per-phase kernels (used only if coop launch fails) -----------
template <bool BF>
__device__ void gemm_phase_body(const void* Wm, const void* Zm, const void* Um,
                                const void* Vm, const void* bnd, float* ws,
                                float* smem, int tau) {
    int t0, k0, m0, a0, n0, t1, k1, m1, a1, n1;
    phase_meta<BF>(bnd, ws, tau, 0, t0, k0, m0, a0, n0);
    phase_meta<BF>(bnd, ws, tau, 1, t1, k1, m1, a1, n1);
    int bid = blockIdx.x;
    if (bid < n0) gemm_slot<BF>(Wm, Zm, Um, Vm, ws, smem, smem + 4352, 0, bid, t0, k0, m0, a0);
    else if (bid < n0 + n1) gemm_slot<BF>(Wm, Zm, Um, Vm, ws, smem, smem + 4352, 1, bid - n0, t1, k1, m1, a1);
}
__global__ __launch_bounds__(256) void gemm_phase_kernel(
    const void* Wm, const void* Zm, const void* Um, const void* Vm,
    const void* bnd, float* ws, int tau) {
    __shared__ float smem[2 * 64 * 68];
    int mode = ((const int*)ws)[0];
    if (mode) gemm_phase_body<true>(Wm, Zm, Um, Vm, bnd, ws, smem, tau);
    else      gemm_phase_body<false>(Wm, Zm, Um, Vm, bnd, ws, smem, tau);
}
template <bool BF>
__device__ void gates_phase_body(const void* xin, const void* Um, const void* Jm,
                                 const void* bbias, const void* bnd, float* ws,
                                 float* smem, int tau) {
    int seg = blockIdx.x >> 7, jblk = blockIdx.x & 127;
    int t, k, mc, az, nb;
    phase_meta<BF>(bnd, ws, tau, seg, t, k, mc, az, nb);
    if (t >= 0)
        gates_slot<BF>(xin, Um, Jm, bbias, ws, smem, seg, jblk, t, k, mc, az);
}
__global__ __launch_bounds__(256) void gates_phase_kernel(
    const void* xin, const void* Um, const void* Jm, const void* bbias,
    const void* bnd, float* ws, int tau) {
    __shared__ float smem[64 * (GG + 1) + 4];
    int mode = ((const int*)ws)[0];
    if (mode) gates_phase_body<true>(xin, Um, Jm, bbias, bnd, ws, smem, tau);
    else      gates_phase_body<false>(xin, Um, Jm, bbias, bnd, ws, smem, tau);
}

// ---- excitation epilogue (hist loader adapted to [tk][j][b]) ---------------
template <bool BF>
__device__ void excite_body(const float* ws, float* smem, const void* Qm,
                            const void* Rm, const void* Wom, const void* bom,
                            void* out) {
    float (*sh_hcat)[LL * HH] = (float (*)[LL * HH])smem;
    float (*sh_r)[HH] = (float (*)[HH])(smem + TT * LL * HH);
    const u16* hhist = (const u16*)(ws + HIST_OFF);
    int tid = threadIdx.x;
    int b = blockIdx.x >> 5;
    int t0 = (blockIdx.x & 31) * TT;

    for (int idx = tid; idx < TT * LL * HH; idx += 256) {
        int tt = idx / (LL * HH);
        int f = idx % (LL * HH);
        int kk = f / HH, j = f % HH;
        sh_hcat[tt][f] = bf2f(hhist[((size_t)((t0 + tt) * 4 + kk) * HH + j) * BB + b]);
    }
    __syncthreads();

    int h0 = tid * 2;
    float acc0[TT] = {0, 0, 0, 0}, acc1[TT] = {0, 0, 0, 0};
    for (int kk = 0; kk < LL; ++kk) {
        float r0[TT] = {0, 0, 0, 0}, r1[TT] = {0, 0, 0, 0};
        if (BF) {
            const u32* qp = (const u32*)((const u16*)Qm + (size_t)kk * (LL * HH) * HH) + tid;
#pragma unroll 4
            for (int f = 0; f < LL * HH; ++f) {
                float2 qv = bf2x2(qp[(size_t)f * 256]);
#pragma unroll
                for (int tt = 0; tt < TT; ++tt) {
                    float hc = sh_hcat[tt][f];
                    r0[tt] += qv.x * hc;
                    r1[tt] += qv.y * hc;
                }
            }
        } else {
            const float2* qp = (const float2*)((const float*)Qm + (size_t)kk * (LL * HH) * HH) + tid;
#pragma unroll 4
            for (int f = 0; f < LL * HH; ++f) {
                float2 qv = qp[(size_t)f * 256];
#pragma unroll
                for (int tt = 0; tt < TT; ++tt) {
                    float hc = sh_hcat[tt][f];
                    r0[tt] += qv.x * hc;
                    r1[tt] += qv.y * hc;
                }
            }
        }
        __syncthreads();
#pragma unroll
        for (int tt = 0; tt < TT; ++tt) {
            sh_r[tt][h0]     = 1.f / (1.f + expf(-r0[tt]));
            sh_r[tt][h0 + 1] = 1.f / (1.f + expf(-r1[tt]));
        }
        __syncthreads();
        float m0[TT] = {0, 0, 0, 0}, m1v[TT] = {0, 0, 0, 0};
        if (BF) {
            const u32* rp = (const u32*)((const u16*)Rm + (size_t)kk * HH * HH) + tid;
#pragma unroll 4
            for (int hh2 = 0; hh2 < HH; ++hh2) {
                float2 rv = bf2x2(rp[(size_t)hh2 * 256]);
#pragma unroll
                for (int tt = 0; tt < TT; ++tt) {
                    float rr = sh_r[tt][hh2];
                    m0[tt] += rv.x * rr;
                    m1v[tt] += rv.y * rr;
                }
            }
        } else {
            const float2* rp = (const float2*)((const float*)Rm + (size_t)kk * HH * HH) + tid;
#pragma unroll 4
            for (int hh2 = 0; hh2 < HH; ++hh2) {
                float2 rv = rp[(size_t)hh2 * 256];
#pragma unroll
                for (int tt = 0; tt < TT; ++tt) {
                    float rr = sh_r[tt][hh2];
                    m0[tt] += rv.x * rr;
                    m1v[tt] += rv.y * rr;
                }
            }
        }
#pragma unroll
        for (int tt = 0; tt < TT; ++tt) {
            acc0[tt] += m0[tt] * sh_hcat[tt][kk * HH + h0];
            acc1[tt] += m1v[tt] * sh_hcat[tt][kk * HH + h0 + 1];
        }
    }
    __syncthreads();
#pragma unroll
    for (int tt = 0; tt < TT; ++tt) {
        sh_r[tt][h0]     = fmaxf(acc0[tt], 0.f);
        sh_r[tt][h0 + 1] = fmaxf(acc1[tt], 0.f);
    }
    __syncthreads();
    {
        int tt = tid >> 6, f = tid & 63;
        float acc = 0.f;
        if (BF) {
            const uint4* wp = (const uint4*)((const u16*)Wom + (size_t)f * HH);
            const float4* ev = (const float4*)sh_r[tt];
#pragma unroll 8
            for (int it = 0; it < HH / 8; ++it) {
                uint4 qv = wp[it];
                float4 e0 = ev[2 * it], e1 = ev[2 * it + 1];
                float2 a0 = bf2x2(qv.x), a1 = bf2x2(qv.y), a2 = bf2x2(qv.z), a3 = bf2x2(qv.w);
                acc += a0.x * e0.x + a0.y * e0.y + a1.x * e0.z + a1.y * e0.w +
                       a2.x * e1.x + a2.y * e1.y + a3.x * e1.z + a3.y * e1.w;
            }
        } else {
            const float4* wp = (const float4*)((const float*)Wom + (size_t)f * HH);
            const float4* ev = (const float4*)sh_r[tt];
#pragma unroll 8
            for (int it = 0; it < HH / 4; ++it) {
                float4 qv = wp[it], e = ev[it];
                acc += qv.x * e.x + qv.y * e.y + qv.z * e.z + qv.w * e.w;
            }
        }
        acc += ldv<BF>(bom, f);
        size_t oidx = ((size_t)b * TS + (t0 + tt)) * FF + f;
        if (BF) ((u16*)out)[oidx] = f2bf_rne(acc);
        else    ((float*)out)[oidx] = acc;
    }
}

__global__ __launch_bounds__(256) void excite_kernel(
    const float* ws, const void* Qm, const void* Rm, const void* Wom,
    const void* bom, void* out) {
    extern __shared__ float smem[];
    int mode = ((const int*)ws)[0];
    if (mode) excite_body<true>(ws, smem, Qm, Rm, Wom, bom, out);
    else      excite_body<false>(ws, smem, Qm, Rm, Wom, bom, out);
}

extern "C" void kernel_launch(void* const* d_in, const int* in_sizes, int n_in,
                              void* d_out, int out_size, void* d_ws, size_t ws_size,
                              hipStream_t stream) {
    const void* xin = d_in[0];
    const void* Wm  = d_in[1];
    const void* Zm  = d_in[2];
    const void* Um  = d_in[3];
    const void* Vm  = d_in[4];
    const void* Jm  = d_in[5];
    const void* bb  = d_in[6];
    const void* bnd = d_in[7];
    const void* Qm  = d_in[8];
    const void* Rm  = d_in[9];
    const void* Wo  = d_in[10];
    const void* bo  = d_in[11];
    float* ws = (float*)d_ws;

    initA_kernel<<<dim3(512), dim3(256), 0, stream>>>((const u16*)bnd, ws);
    initB_kernel<<<dim3(512), dim3(64), 0, stream>>>(xin, ws);

    void* args[9] = {(void*)&xin, (void*)&Wm, (void*)&Zm, (void*)&Um, (void*)&Vm,
                     (void*)&Jm, (void*)&bb, (void*)&bnd, (void*)&ws};
    hipError_t cerr = hipLaunchCooperativeKernel(
        reinterpret_cast<const void*>(&scan_kernel), dim3(512), dim3(256),
        args, 0, stream);
    if (cerr != hipSuccess) {
        // fallback: per-phase dispatch pairs (round-4 structure, improved gates)
        for (int tau = 0; tau < 2 * TS + LL - 2; ++tau) {
            gemm_phase_kernel<<<dim3(768), dim3(256), 0, stream>>>(Wm, Zm, Um, Vm, bnd, ws, tau);
            gates_phase_kernel<<<dim3(256), dim3(256), 0, stream>>>(xin, Um, Jm, bb, bnd, ws, tau);
        }
    }

    size_t exc_smem = (TT * LL * HH + TT * HH) * sizeof(float);  // 40 KB
    excite_kernel<<<dim3(2048), dim3(256), exc_smem, stream>>>(
        ws, Qm, Rm, Wo, bo, d_out);
}

// Round 6
// 6667.493 us; speedup vs baseline: 8.4946x; 8.4946x over previous
//
#include <hip/hip_runtime.h>
#include <hip/hip_bf16.h>

// ---------------------------------------------------------------------------
// StandardMRALSTM — round 6: R4 dispatch skeleton + split-bf16 MFMA scan GEMM.
//  * R5 lesson (measured): grid.sync/threadfence on 8 XCDs = ~51us/barrier ->
//    persistent coop kernel abandoned; per-phase dispatch (~5.5us) is cheaper.
//  * BF mode: weights exact bf16; h split hi+lo bf16; 2x mfma_f32_16x16x32_bf16
//    per K32 chunk, fp32 accum. fp32-input mode keeps R4 scalar path.
//  * Gates: R5's single-atomic + coalesced [tk][j][b] hist (validated in R5).
// ---------------------------------------------------------------------------

#define LL 4
#define HH 512
#define TS 128
#define GG 16
#define BB 64
#define FF 64
#define TT 4
#define FIVE_H 2560
#define LBH (LL * BB * HH)

typedef unsigned short u16;
typedef unsigned int u32;
typedef unsigned long long u64;

typedef short bfrag8 __attribute__((ext_vector_type(8)));   // 8 bf16
typedef float facc4 __attribute__((ext_vector_type(4)));    // 4 fp32

#define SG_OFF    64
#define ZALL_OFF  1024
#define ZMASK_OFF 2048
#define C_OFF     4096
#define PING_OFF  (C_OFF + LBH)                       // 135168
#define PART_OFF  (PING_OFF + 2 * LBH)                // 397312
#define PART_SEG  (12 * 4 * HH * BB)                  // 1572864 floats per seg
#define HIST_OFF  (PART_OFF + 2 * PART_SEG)           // 3543040 (u16 region)

__device__ __forceinline__ float bf2f(u16 u) { return __uint_as_float(((u32)u) << 16); }
__device__ __forceinline__ float2 bf2x2(u32 u) {
    float2 r;
    r.x = __uint_as_float(u << 16);
    r.y = __uint_as_float(u & 0xFFFF0000u);
    return r;
}
__device__ __forceinline__ u16 f2bf_rne(float f) {
    u32 x = __float_as_uint(f);
    return (u16)((x + 0x7FFFu + ((x >> 16) & 1u)) >> 16);
}
__device__ __forceinline__ float sigm(float x) { return 1.f / (1.f + expf(-x)); }

template <bool BF>
__device__ __forceinline__ float ldv(const void* p, size_t i) {
    return BF ? bf2f(((const u16*)p)[i]) : ((const float*)p)[i];
}

template <bool BF>
__device__ __forceinline__ float dot16(const void* row, const float* xs) {
    float s = 0.f;
    if (BF) {
        const uint4* p = (const uint4*)row;
        uint4 a = p[0], b4 = p[1];
        float2 v;
        v = bf2x2(a.x);  s += v.x * xs[0]  + v.y * xs[1];
        v = bf2x2(a.y);  s += v.x * xs[2]  + v.y * xs[3];
        v = bf2x2(a.z);  s += v.x * xs[4]  + v.y * xs[5];
        v = bf2x2(a.w);  s += v.x * xs[6]  + v.y * xs[7];
        v = bf2x2(b4.x); s += v.x * xs[8]  + v.y * xs[9];
        v = bf2x2(b4.y); s += v.x * xs[10] + v.y * xs[11];
        v = bf2x2(b4.z); s += v.x * xs[12] + v.y * xs[13];
        v = bf2x2(b4.w); s += v.x * xs[14] + v.y * xs[15];
    } else {
        const float4* p = (const float4*)row;
#pragma unroll
        for (int i = 0; i < 4; ++i) {
            float4 v = p[i];
            s += v.x * xs[4 * i] + v.y * xs[4 * i + 1] + v.z * xs[4 * i + 2] + v.w * xs[4 * i + 3];
        }
    }
    return s;
}

// ---- init A ----------------------------------------------------------------
__global__ void initA_kernel(const u16* __restrict__ bnd_raw, float* __restrict__ ws) {
    size_t i = (size_t)blockIdx.x * 256 + threadIdx.x;
    if (i < LBH) ws[C_OFF + i] = 0.f;
    if (i < 512) ws[SG_OFF + i] = 0.f;
    if (i == 0) {
        int bf = 1;
        for (int j = 0; j < 32; ++j) {
            float v = bf2f(bnd_raw[2 * j]);
            if (!(v >= 0.f && v <= 1.f)) bf = 0;
        }
        ((int*)ws)[0] = bf;
    }
}

// ---- init B ----------------------------------------------------------------
template <bool BF>
__device__ void initB_body(const void* xin, float* ws) {
    int tk = blockIdx.x;
    int t = tk >> 2, k = tk & 3;
    int b = threadIdx.x;
    bool z = false;
    size_t base = (size_t)b * TS * FF + (size_t)t * FF + k * GG;
#pragma unroll
    for (int g = 0; g < GG; ++g) {
        float v = ldv<BF>(xin, base + g);
        z |= !(v != v);
    }
    u64 m = __ballot(z);
    if (b == 0) {
        ((u64*)(ws + ZMASK_OFF))[tk] = m;
        ((int*)(ws + ZALL_OFF))[tk] = (m == ~0ull) ? 1 : 0;
    }
}
__global__ __launch_bounds__(64) void initB_kernel(const void* xin, float* ws) {
    int mode = ((const int*)ws)[0];
    if (mode) initB_body<true>(xin, ws);
    else      initB_body<false>(xin, ws);
}

// ---- per-phase metadata ----------------------------------------------------
template <bool BF>
__device__ __forceinline__ void phase_meta(const void* bnd, const float* ws,
                                           int tau, int s,
                                           int& t, int& k, int& mcase, int& azf, int& nblk) {
    k = (tau & 1) + 2 * s;
    t = (tau - k) >> 1;
    mcase = 4; azf = 0; nblk = 0;
    if (t < 0 || t >= TS) { t = -1; return; }
    const float* sgsum = ws + SG_OFF;
    bool p_hi = (t == 0) ? (ldv<BF>(bnd, (size_t)k * TS) > 0.5f) : (sgsum[(t - 1) * 4 + k] > 16384.f);
    bool l_hi = (k == 0) ? (ldv<BF>(bnd, (size_t)t) > 0.5f) : (sgsum[t * 4 + (k - 1)] > 16384.f);
    mcase = p_hi ? (l_hi ? 3 : 2) : (l_hi ? 1 : 4);
    azf = ((const int*)(ws + ZALL_OFF))[t * 4 + k] ? 0 : 1;
    if (mcase == 4) return;
    int gs = (mcase == 1) ? 0 : 1, ng = 4 - gs;
    int nW = (t > 0) ? ng : 0;
    int nU = ((mcase == 1 || mcase == 3) && k > 0) ? ng : 0;
    int nV = azf ? nU : 0;
    nblk = (nW + nU + nV) * 32;
}

// ---- unit -> (matrix, gate) routing (shared by both gemm paths) ------------
struct SlotInfo {
    const u16* M16; const float* Mf; int RS; int path; int g;
    const float* hv;
};
template <bool BF>
__device__ __forceinline__ SlotInfo slot_info(
    const void* Wm, const void* Zm, const void* Um, const void* Vm,
    const float* ws, int unit, int t, int k, int mcase) {
    int gs = (mcase == 1) ? 0 : 1, ng = 4 - gs;
    int nW = (t > 0) ? ng : 0;
    int nU = ((mcase == 1 || mcase == 3) && k > 0) ? ng : 0;
    int mat, g;
    if (unit < nW)            { mat = (mcase == 1) ? 0 : 1; g = gs + unit; }
    else if (unit < nW + nU)  { mat = 2; g = gs + unit - nW; }
    else                      { mat = 3; g = gs + unit - nW - nU; }
    const void* M = (mat == 0) ? Wm : (mat == 1) ? Zm : (mat == 2) ? Um : Vm;
    int kn = (k + 1 < LL) ? k + 1 : LL - 1;
    const float* ping = ws + PING_OFF;
    const float* prev = ping + (size_t)((t + 1) & 1) * LBH;   // [k][c][b]
    const float* cur  = ping + (size_t)(t & 1) * LBH;
    SlotInfo si;
    si.M16 = (const u16*)M; si.Mf = (const float*)M;
    si.RS = (mat == 2) ? (HH + GG) : HH;
    si.path = (mat <= 1) ? 0 : (mat == 2 ? 1 : 2);
    si.g = g;
    si.hv = (mat == 0) ? prev + (size_t)k * HH * BB
          : (mat == 1) ? prev + (size_t)kn * HH * BB
                       : cur + (size_t)(k - 1) * HH * BB;
    return si;
}

// ---- MFMA gemm slot (BF mode) ---------------------------------------------
// LDS: wt u16[64][152] (A tiles, row-major, stride avoids >2-way conflicts)
//      hB u16[2 part][16 kbq][4 bg][16 n][8 j]  (B-fragment layout, hi|lo)
#define WT_STRIDE 152
#define HB_OFF 9728                       // u16 offset of hB within gsm
#define HB_PART 8192                      // u16 per part
__device__ void gemm_slot_bf(const void* Wm, const void* Zm, const void* Um, const void* Vm,
                             float* ws, u16* gsm,
                             int seg, int idx, int t, int k, int mcase) {
    int tid = threadIdx.x;
    int q = idx & 3, sub = (idx >> 2) & 7, unit = idx >> 5;
    SlotInfo si = slot_info<true>(Wm, Zm, Um, Vm, ws, unit, t, k, mcase);
    int gbase = (si.g < 3) ? si.g * 512 : 2048;
    size_t mbase = (size_t)k * FIVE_H * si.RS + (size_t)(gbase + sub * 64) * si.RS + q * 128;
    u16* wt = gsm;
    u16* hB = gsm + HB_OFF;

    // stage weights: 64 rows x 128 k (bf16, already exact)
    {
        int r = tid >> 2, c0 = (tid & 3) * 32;
        const u16* src = si.M16 + mbase + (size_t)r * si.RS + c0;
#pragma unroll
        for (int i = 0; i < 4; ++i)
            *(uint4*)&wt[r * WT_STRIDE + c0 + 8 * i] = *(const uint4*)(src + 8 * i);
    }
    // stage h: fp32 [c][b] -> hi/lo bf16 in B-frag layout (coalesced reads,
    // lane-local pack, single b128 write per part)
    {
        int wave = tid >> 6, lane = tid & 63;
        int bg = lane >> 4, n = lane & 15;
#pragma unroll
        for (int it = 0; it < 4; ++it) {
            int kbq = it * 4 + wave;
            u32 hiw[4], low[4];
#pragma unroll
            for (int jp = 0; jp < 4; ++jp) {
                float v0 = si.hv[(size_t)(q * 128 + kbq * 8 + 2 * jp) * BB + lane];
                float v1 = si.hv[(size_t)(q * 128 + kbq * 8 + 2 * jp + 1) * BB + lane];
                u16 h0 = f2bf_rne(v0), h1 = f2bf_rne(v1);
                u16 l0 = f2bf_rne(v0 - bf2f(h0)), l1 = f2bf_rne(v1 - bf2f(h1));
                hiw[jp] = (u32)h0 | ((u32)h1 << 16);
                low[jp] = (u32)l0 | ((u32)l1 << 16);
            }
            int base = (kbq * 4 + bg) * 128 + n * 8;
            *(uint4*)&hB[base] = make_uint4(hiw[0], hiw[1], hiw[2], hiw[3]);
            *(uint4*)&hB[HB_PART + base] = make_uint4(low[0], low[1], low[2], low[3]);
        }
    }
    __syncthreads();

    int wave = tid >> 6, lane = tid & 63;
    int m = lane & 15, qd = lane >> 4;
    facc4 acc[4];
#pragma unroll
    for (int i = 0; i < 4; ++i) acc[i] = (facc4){0.f, 0.f, 0.f, 0.f};
#pragma unroll
    for (int kb = 0; kb < 4; ++kb) {
        bfrag8 a = *(const bfrag8*)&wt[(wave * 16 + m) * WT_STRIDE + kb * 32 + qd * 8];
        int kbq = kb * 4 + qd;
#pragma unroll
        for (int bg = 0; bg < 4; ++bg) {
            bfrag8 bh = *(const bfrag8*)&hB[(kbq * 4 + bg) * 128 + m * 8];
            bfrag8 bl = *(const bfrag8*)&hB[HB_PART + (kbq * 4 + bg) * 128 + m * 8];
            acc[bg] = __builtin_amdgcn_mfma_f32_16x16x32_bf16(a, bh, acc[bg], 0, 0, 0);
            acc[bg] = __builtin_amdgcn_mfma_f32_16x16x32_bf16(a, bl, acc[bg], 0, 0, 0);
        }
    }
    // D: row = qd*4+reg (j within 16), col = m (b within 16)  [m89-verified]
    float* pout = ws + PART_OFF + (size_t)seg * PART_SEG +
                  ((size_t)(si.path * 4 + q) * 4 + si.g) * (size_t)HH * BB;
#pragma unroll
    for (int bg = 0; bg < 4; ++bg)
#pragma unroll
        for (int reg = 0; reg < 4; ++reg)
            pout[(size_t)(sub * 64 + wave * 16 + qd * 4 + reg) * BB + bg * 16 + m] = acc[bg][reg];
}

// ---- fp32 gemm slot (fallback mode, R4-proven) -----------------------------
__device__ void gemm_slot_f32(const void* Wm, const void* Zm, const void* Um, const void* Vm,
                              float* ws, float* wt, float* ht,
                              int seg, int idx, int t, int k, int mcase) {
    int tid = threadIdx.x;
    int q = idx & 3, sub = (idx >> 2) & 7, unit = idx >> 5;
    SlotInfo si = slot_info<false>(Wm, Zm, Um, Vm, ws, unit, t, k, mcase);
    int gbase = (si.g < 3) ? si.g * 512 : 2048;
    size_t mbase = (size_t)k * FIVE_H * si.RS + (size_t)(gbase + sub * 64) * si.RS + q * 128;

    int rg = tid >> 4, bg = tid & 15;
    float acc[4][4] = {{0.f}};
    for (int half = 0; half < 2; ++half) {
        int sr = tid >> 2, scg = (tid & 3) * 16;
        size_t rowoff = mbase + (size_t)sr * si.RS + half * 64 + scg;
#pragma unroll
        for (int i = 0; i < 4; ++i)
            *(float4*)&wt[sr * 68 + scg + 4 * i] = *(const float4*)(si.Mf + rowoff + 4 * i);
        int hc = tid >> 2, hb = (tid & 3) * 16;
        const float* hrow = si.hv + (size_t)(q * 128 + half * 64 + hc) * BB + hb;
#pragma unroll
        for (int i = 0; i < 4; ++i)
            *(float4*)&ht[hc * 68 + hb + 4 * i] = *(const float4*)(hrow + 4 * i);
        __syncthreads();
#pragma unroll 4
        for (int kk4 = 0; kk4 < 64; kk4 += 4) {
            float w[4][4], h[4][4];
#pragma unroll
            for (int j = 0; j < 4; ++j)
                *(float4*)w[j] = *(const float4*)&wt[(rg * 4 + j) * 68 + kk4];
#pragma unroll
            for (int j = 0; j < 4; ++j)
                *(float4*)h[j] = *(const float4*)&ht[(kk4 + j) * 68 + bg * 4];
#pragma unroll
            for (int rj = 0; rj < 4; ++rj)
#pragma unroll
                for (int bj = 0; bj < 4; ++bj)
#pragma unroll
                    for (int j = 0; j < 4; ++j)
                        acc[rj][bj] += w[rj][j] * h[j][bj];
        }
        __syncthreads();
    }
    float* pout = ws + PART_OFF + (size_t)seg * PART_SEG +
                  ((size_t)(si.path * 4 + q) * 4 + si.g) * (size_t)HH * BB;
#pragma unroll
    for (int rj = 0; rj < 4; ++rj) {
        float4 vv = make_float4(acc[rj][0], acc[rj][1], acc[rj][2], acc[rj][3]);
        *(float4*)&pout[(size_t)(sub * 64 + rg * 4 + rj) * BB + bg * 4] = vv;
    }
}

__global__ __launch_bounds__(256) void gemm_phase_kernel(
    const void* Wm, const void* Zm, const void* Um, const void* Vm,
    const void* bnd, float* ws, int tau) {
    __shared__ __align__(16) u16 gsm[26112];   // 52224 B: wt 64x152 | hB 2x8192
    int mode = ((const int*)ws)[0];
    if (mode) {
        int t0, k0, m0, a0, n0, t1, k1, m1, a1, n1;
        phase_meta<true>(bnd, ws, tau, 0, t0, k0, m0, a0, n0);
        phase_meta<true>(bnd, ws, tau, 1, t1, k1, m1, a1, n1);
        int bid = blockIdx.x;
        if (bid < n0)           gemm_slot_bf(Wm, Zm, Um, Vm, ws, gsm, 0, bid, t0, k0, m0);
        else if (bid < n0 + n1) gemm_slot_bf(Wm, Zm, Um, Vm, ws, gsm, 1, bid - n0, t1, k1, m1);
    } else {
        float* fs = (float*)gsm;
        int t0, k0, m0, a0, n0, t1, k1, m1, a1, n1;
        phase_meta<false>(bnd, ws, tau, 0, t0, k0, m0, a0, n0);
        phase_meta<false>(bnd, ws, tau, 1, t1, k1, m1, a1, n1);
        int bid = blockIdx.x;
        if (bid < n0)           gemm_slot_f32(Wm, Zm, Um, Vm, ws, fs, fs + 4352, 0, bid, t0, k0, m0);
        else if (bid < n0 + n1) gemm_slot_f32(Wm, Zm, Um, Vm, ws, fs, fs + 4352, 1, bid - n0, t1, k1, m1);
    }
}

// ---- gates slot (R5-validated: single atomic, coalesced hist) --------------
template <bool BF>
__device__ void gates_slot(const void* xin, const void* Um, const void* Jm,
                           const void* bbias, float* ws, float* smem,
                           int seg, int jblk, int t, int k, int mcase, int azf) {
    float (*xs)[GG + 1] = (float (*)[GG + 1])smem;
    float* red = smem + BB * (GG + 1);
    int tid = threadIdx.x;
    int j = jblk * 4 + (tid >> 6);
    int b = tid & 63;

    {
        int b2 = tid >> 2, i0 = (tid & 3) * 4;
#pragma unroll
        for (int i = 0; i < 4; ++i) {
            float v = ldv<BF>(xin, (size_t)b2 * TS * FF + (size_t)t * FF + k * GG + i0 + i);
            xs[b2][i0 + i] = (v != v) ? 0.f : v;
        }
    }
    __syncthreads();
    u64 zm = ((const u64*)(ws + ZMASK_OFF))[t * 4 + k];
    bool zb = (zm >> b) & 1ull;

    float* cbuf = ws + C_OFF;
    const float* part = ws + PART_OFF + (size_t)seg * PART_SEG;
    float* cur = ws + PING_OFF + (size_t)(t & 1) * LBH;
    const float* prev = ws + PING_OFF + (size_t)((t + 1) & 1) * LBH;
    u16* hist = (u16*)(ws + HIST_OFF);
    size_t sidx = ((size_t)k * HH + j) * BB + b;

    float hn, sgv;
    if (mcase == 4) {
        float c = cbuf[sidx];
        float o = sigm(ldv<BF>(bbias, (size_t)k * FIVE_H + 1536 + j));
        hn = o * tanhf(c);
        float bsg = ldv<BF>(bbias, (size_t)k * FIVE_H + 2048 + j);
        sgv = fminf(fmaxf((bsg + 1.f) * 0.5f, 0.f), 1.f);
    } else {
        bool hasWZ = (t > 0);
        bool hasU = (k > 0) && (mcase != 2);
        const float* xv = &xs[b][0];
        auto psum = [&](int path, int g) -> float {
            float s = 0.f;
#pragma unroll
            for (int qq = 0; qq < 4; ++qq)
                s += part[(((size_t)(path * 4 + qq) * 4 + g) * HH + j) * BB + b];
            return s;
        };
        auto pre = [&](int g) -> float {
            int gb = (g < 3) ? g * 512 : 2048;
            float s = ldv<BF>(bbias, (size_t)k * FIVE_H + gb + j);
            if (hasWZ) s += psum(0, g);
            if (mcase == 2) {
                if (zb) {
                    const void* row = BF ? (const void*)((const u16*)Jm + (size_t)k * FIVE_H * GG + (size_t)(gb + j) * GG)
                                         : (const void*)((const float*)Jm + (size_t)k * FIVE_H * GG + (size_t)(gb + j) * GG);
                    s += dot16<BF>(row, xv);
                }
            } else {
                if (zb) {
                    if (hasU) s += psum(1, g);
                    const void* row = BF ? (const void*)((const u16*)Um + (size_t)k * FIVE_H * (HH + GG) + (size_t)(gb + j) * (HH + GG) + HH)
                                         : (const void*)((const float*)Um + (size_t)k * FIVE_H * (HH + GG) + (size_t)(gb + j) * (HH + GG) + HH);
                    s += dot16<BF>(row, xv);
                } else {
                    if (hasU && azf) s += psum(2, g);
                }
            }
            return s;
        };
        float preg = pre(1), prei = pre(2), presg = pre(3);
        float gg = tanhf(preg), ii = sigm(prei);
        float cnew;
        if (mcase == 1) {
            float f = sigm(pre(0));
            cnew = f * cbuf[sidx] + ii * gg;
        } else {
            cnew = ii * gg;
        }
        cbuf[sidx] = cnew;
        hn = (t > 0) ? prev[sidx] : 0.f;
        sgv = fminf(fmaxf((presg + 1.f) * 0.5f, 0.f), 1.f);
    }
    cur[sidx] = hn;
    hist[((size_t)(t * 4 + k) * HH + j) * BB + b] = f2bf_rne(hn);

    float s = sgv;
#pragma unroll
    for (int off = 32; off > 0; off >>= 1) s += __shfl_down(s, off);
    if ((tid & 63) == 0) red[tid >> 6] = s;
    __syncthreads();
    if (tid == 0)
        atomicAdd(&ws[SG_OFF + t * 4 + k], red[0] + red[1] + red[2] + red[3]);
}

template <bool BF>
__device__ void gates_phase_body(const void* xin, const void* Um, const void* Jm,
                                 const void* bbias, const void* bnd, float* ws,
                                 float* smem, int tau) {
    int seg = blockIdx.x >> 7, jblk = blockIdx.x & 127;
    int t, k, mc, az, nb;
    phase_meta<BF>(bnd, ws, tau, seg, t, k, mc, az, nb);
    if (t >= 0)
        gates_slot<BF>(xin, Um, Jm, bbias, ws, smem, seg, jblk, t, k, mc, az);
}
__global__ __launch_bounds__(256) void gates_phase_kernel(
    const void* xin, const void* Um, const void* Jm, const void* bbias,
    const void* bnd, float* ws, int tau) {
    __shared__ float smem[BB * (GG + 1) + 4];
    int mode = ((const int*)ws)[0];
    if (mode) gates_phase_body<true>(xin, Um, Jm, bbias, bnd, ws, smem, tau);
    else      gates_phase_body<false>(xin, Um, Jm, bbias, bnd, ws, smem, tau);
}

// ---- excitation epilogue (unchanged, R5-validated hist layout) -------------
template <bool BF>
__device__ void excite_body(const float* ws, float* smem, const void* Qm,
                            const void* Rm, const void* Wom, const void* bom,
                            void* out) {
    float (*sh_hcat)[LL * HH] = (float (*)[LL * HH])smem;
    float (*sh_r)[HH] = (float (*)[HH])(smem + TT * LL * HH);
    const u16* hhist = (const u16*)(ws + HIST_OFF);
    int tid = threadIdx.x;
    int b = blockIdx.x >> 5;
    int t0 = (blockIdx.x & 31) * TT;

    for (int idx = tid; idx < TT * LL * HH; idx += 256) {
        int tt = idx / (LL * HH);
        int f = idx % (LL * HH);
        int kk = f / HH, j = f % HH;
        sh_hcat[tt][f] = bf2f(hhist[((size_t)((t0 + tt) * 4 + kk) * HH + j) * BB + b]);
    }
    __syncthreads();

    int h0 = tid * 2;
    float acc0[TT] = {0, 0, 0, 0}, acc1[TT] = {0, 0, 0, 0};
    for (int kk = 0; kk < LL; ++kk) {
        float r0[TT] = {0, 0, 0, 0}, r1[TT] = {0, 0, 0, 0};
        if (BF) {
            const u32* qp = (const u32*)((const u16*)Qm + (size_t)kk * (LL * HH) * HH) + tid;
#pragma unroll 4
            for (int f = 0; f < LL * HH; ++f) {
                float2 qv = bf2x2(qp[(size_t)f * 256]);
#pragma unroll
                for (int tt = 0; tt < TT; ++tt) {
                    float hc = sh_hcat[tt][f];
                    r0[tt] += qv.x * hc;
                    r1[tt] += qv.y * hc;
                }
            }
        } else {
            const float2* qp = (const float2*)((const float*)Qm + (size_t)kk * (LL * HH) * HH) + tid;
#pragma unroll 4
            for (int f = 0; f < LL * HH; ++f) {
                float2 qv = qp[(size_t)f * 256];
#pragma unroll
                for (int tt = 0; tt < TT; ++tt) {
                    float hc = sh_hcat[tt][f];
                    r0[tt] += qv.x * hc;
                    r1[tt] += qv.y * hc;
                }
            }
        }
        __syncthreads();
#pragma unroll
        for (int tt = 0; tt < TT; ++tt) {
            sh_r[tt][h0]     = 1.f / (1.f + expf(-r0[tt]));
            sh_r[tt][h0 + 1] = 1.f / (1.f + expf(-r1[tt]));
        }
        __syncthreads();
        float m0[TT] = {0, 0, 0, 0}, m1v[TT] = {0, 0, 0, 0};
        if (BF) {
            const u32* rp = (const u32*)((const u16*)Rm + (size_t)kk * HH * HH) + tid;
#pragma unroll 4
            for (int hh2 = 0; hh2 < HH; ++hh2) {
                float2 rv = bf2x2(rp[(size_t)hh2 * 256]);
#pragma unroll
                for (int tt = 0; tt < TT; ++tt) {
                    float rr = sh_r[tt][hh2];
                    m0[tt] += rv.x * rr;
                    m1v[tt] += rv.y * rr;
                }
            }
        } else {
            const float2* rp = (const float2*)((const float*)Rm + (size_t)kk * HH * HH) + tid;
#pragma unroll 4
            for (int hh2 = 0; hh2 < HH; ++hh2) {
                float2 rv = rp[(size_t)hh2 * 256];
#pragma unroll
                for (int tt = 0; tt < TT; ++tt) {
                    float rr = sh_r[tt][hh2];
                    m0[tt] += rv.x * rr;
                    m1v[tt] += rv.y * rr;
                }
            }
        }
#pragma unroll
        for (int tt = 0; tt < TT; ++tt) {
            acc0[tt] += m0[tt] * sh_hcat[tt][kk * HH + h0];
            acc1[tt] += m1v[tt] * sh_hcat[tt][kk * HH + h0 + 1];
        }
    }
    __syncthreads();
#pragma unroll
    for (int tt = 0; tt < TT; ++tt) {
        sh_r[tt][h0]     = fmaxf(acc0[tt], 0.f);
        sh_r[tt][h0 + 1] = fmaxf(acc1[tt], 0.f);
    }
    __syncthreads();
    {
        int tt = tid >> 6, f = tid & 63;
        float acc = 0.f;
        if (BF) {
            const uint4* wp = (const uint4*)((const u16*)Wom + (size_t)f * HH);
            const float4* ev = (const float4*)sh_r[tt];
#pragma unroll 8
            for (int it = 0; it < HH / 8; ++it) {
                uint4 qv = wp[it];
                float4 e0 = ev[2 * it], e1 = ev[2 * it + 1];
                float2 a0 = bf2x2(qv.x), a1 = bf2x2(qv.y), a2 = bf2x2(qv.z), a3 = bf2x2(qv.w);
                acc += a0.x * e0.x + a0.y * e0.y + a1.x * e0.z + a1.y * e0.w +
                       a2.x * e1.x + a2.y * e1.y + a3.x * e1.z + a3.y * e1.w;
            }
        } else {
            const float4* wp = (const float4*)((const float*)Wom + (size_t)f * HH);
            const float4* ev = (const float4*)sh_r[tt];
#pragma unroll 8
            for (int it = 0; it < HH / 4; ++it) {
                float4 qv = wp[it], e = ev[it];
                acc += qv.x * e.x + qv.y * e.y + qv.z * e.z + qv.w * e.w;
            }
        }
        acc += ldv<BF>(bom, f);
        size_t oidx = ((size_t)b * TS + (t0 + tt)) * FF + f;
        if (BF) ((u16*)out)[oidx] = f2bf_rne(acc);
        else    ((float*)out)[oidx] = acc;
    }
}

__global__ __launch_bounds__(256) void excite_kernel(
    const float* ws, const void* Qm, const void* Rm, const void* Wom,
    const void* bom, void* out) {
    extern __shared__ float smem[];
    int mode = ((const int*)ws)[0];
    if (mode) excite_body<true>(ws, smem, Qm, Rm, Wom, bom, out);
    else      excite_body<false>(ws, smem, Qm, Rm, Wom, bom, out);
}

extern "C" void kernel_launch(void* const* d_in, const int* in_sizes, int n_in,
                              void* d_out, int out_size, void* d_ws, size_t ws_size,
                              hipStream_t stream) {
    const void* xin = d_in[0];
    const void* Wm  = d_in[1];
    const void* Zm  = d_in[2];
    const void* Um  = d_in[3];
    const void* Vm  = d_in[4];
    const void* Jm  = d_in[5];
    const void* bb  = d_in[6];
    const void* bnd = d_in[7];
    const void* Qm  = d_in[8];
    const void* Rm  = d_in[9];
    const void* Wo  = d_in[10];
    const void* bo  = d_in[11];
    float* ws = (float*)d_ws;

    initA_kernel<<<dim3(512), dim3(256), 0, stream>>>((const u16*)bnd, ws);
    initB_kernel<<<dim3(512), dim3(64), 0, stream>>>(xin, ws);
    for (int tau = 0; tau < 2 * TS + LL - 2; ++tau) {   // 258 phases
        gemm_phase_kernel<<<dim3(768), dim3(256), 0, stream>>>(Wm, Zm, Um, Vm, bnd, ws, tau);
        gates_phase_kernel<<<dim3(256), dim3(256), 0, stream>>>(xin, Um, Jm, bb, bnd, ws, tau);
    }
    size_t exc_smem = (TT * LL * HH + TT * HH) * sizeof(float);  // 40 KB
    excite_kernel<<<dim3(2048), dim3(256), exc_smem, stream>>>(
        ws, Qm, Rm, Wo, bo, d_out);
}